// Round 12
// baseline (149.485 us; speedup 1.0000x reference)
//
#include <hip/hip_runtime.h>

#define CPG 8
#define NGRP 32
#define NB 16
#define HW 3136
#define HU 784       // float4 units per channel image
#define N2 36
#define N3 120
#define NF 165       // 164 poly features + 1 summed-bias row
#define WSTRIDE (NF * CPG)   // 1320 floats per group in ws

typedef float vfloat4 __attribute__((ext_vector_type(4)));

__host__ __device__ constexpr int idx2(int i, int j) {
    return i * CPG - i * (i - 1) / 2 + (j - i);
}
__host__ __device__ constexpr int idx3(int a, int b, int c) {
    int base = 0;
    for (int t = 0; t < a; ++t) { int m = CPG - t; base += m * (m + 1) / 2; }
    for (int t = a; t < b; ++t) base += CPG - t;
    return base + (c - b);
}

__device__ inline vfloat4 splat4(float s) { return (vfloat4){s, s, s, s}; }

// ---------------------------------------------------------------------------
// prep: transpose weights to ws[g][f][o] (f-major, 8 contiguous outputs per
// feature) so weight reads are contiguous scalar loads.
// f 0-7: deg1, 8-43: deg2, 44-163: deg3, 164: b1+b2+b3
// ---------------------------------------------------------------------------
__global__ __launch_bounds__(256) void prep_weights(
    const float* __restrict__ w1, const float* __restrict__ b1,
    const float* __restrict__ w2, const float* __restrict__ b2,
    const float* __restrict__ w3, const float* __restrict__ b3,
    float* __restrict__ ws)
{
    const int g = blockIdx.x;
    for (int idx = threadIdx.x; idx < WSTRIDE; idx += 256) {
        const int f = idx >> 3, o = idx & 7;
        const int ch = g * CPG + o;
        float v;
        if (f < 8)        v = w1[ch * CPG + f];
        else if (f < 44)  v = w2[ch * N2 + (f - 8)];
        else if (f < 164) v = w3[ch * N3 + (f - 44)];
        else              v = b1[ch] + b2[ch] + b3[ch];
        ws[g * WSTRIDE + idx] = v;
    }
}

// 4-output block: one s_load_dwordx4 per feature, 16 fmacs.
#define ACCUMS4(F, T) do {                                                   \
    const float w0 = wp[(F) * 8 + 0], w1_ = wp[(F) * 8 + 1];                 \
    const float w2_ = wp[(F) * 8 + 2], w3_ = wp[(F) * 8 + 3];                \
    acc[0] += w0  * (T); acc[1] += w1_ * (T);                                \
    acc[2] += w2_ * (T); acc[3] += w3_ * (T);                                \
} while (0)

// Output-half split: each block does 4 of the 8 outputs.
//  - live set xv(32)+acc(16)+temps ~58 regs: holdable -> no mid-body x reloads
//    (R3/R11 showed VGPR_Count 44-52 < the 64-reg array set => allocator was
//    re-loading xv from memory all session; that is the persistent ~48% stall)
//  - body halves to ~13 KB: fits shared I$ with reuse
// waves_per_eu(2,6): caps allocator wave-chasing at 6/SIMD (budget ~85 regs)
// so it keeps the arrays resident instead of starving to 44.
__global__ __launch_bounds__(256)
__attribute__((amdgpu_waves_per_eu(2, 6)))
void hoaf_sload4(
    const float* __restrict__ x,
    const float* __restrict__ ws,
    float* __restrict__ out)
{
    const int tid   = threadIdx.x;
    const int g     = blockIdx.x;   // block-uniform group
    const int b     = blockIdx.y;
    const int z     = blockIdx.z;   // 0..7: (half, chunk)
    const int chunk = z & 3;        // 0..3; chunk 3 is a 16-unit runt
    const int h4    = (z >> 2) * 4; // output half: 0 or 4

    const int q = tid + chunk * 256;   // one float4 body per thread
    if (q >= HU) return;

    const float* __restrict__ wp = ws + g * WSTRIDE + h4;  // uniform -> s_load

    const size_t base = ((size_t)(b * NGRP + g) * CPG) * HW;
    const vfloat4* x4 = (const vfloat4*)(x + base);
    vfloat4*       o4 = (vfloat4*)(out + base) + (size_t)h4 * HU;

    vfloat4 xv[CPG];
#pragma unroll
    for (int c = 0; c < CPG; ++c) xv[c] = x4[(size_t)c * HU + q];

    vfloat4 acc[4];
#pragma unroll
    for (int o = 0; o < 4; ++o) acc[o] = splat4(wp[164 * 8 + o]);

    // degree 1
#pragma unroll
    for (int k = 0; k < CPG; ++k) ACCUMS4(k, xv[k]);

    // degree 2 & 3: pair product (i<=j) feeds triples (a<=i<=j)
#pragma unroll
    for (int i = 0; i < CPG; ++i) {
#pragma unroll
        for (int j = i; j < CPG; ++j) {
            const vfloat4 p = xv[i] * xv[j];
            ACCUMS4(8 + idx2(i, j), p);
#pragma unroll
            for (int a = 0; a <= i; ++a) {
                const vfloat4 t = xv[a] * p;
                ACCUMS4(44 + idx3(a, i, j), t);
            }
        }
    }

#pragma unroll
    for (int o = 0; o < 4; ++o) o4[(size_t)o * HU + q] = acc[o];
}

// ---------------------------------------------------------------------------
// Fallback (workspace too small): R3 kernel verbatim — known-good 68.5 us.
// ---------------------------------------------------------------------------
#define ACCUM(F, T) do {                                                       \
    const vfloat4 wa = *reinterpret_cast<const vfloat4*>(&wt[(F)][0]);         \
    const vfloat4 wb = *reinterpret_cast<const vfloat4*>(&wt[(F)][4]);         \
    acc[0] += wa.x * (T); acc[1] += wa.y * (T);                                \
    acc[2] += wa.z * (T); acc[3] += wa.w * (T);                                \
    acc[4] += wb.x * (T); acc[5] += wb.y * (T);                                \
    acc[6] += wb.z * (T); acc[7] += wb.w * (T);                                \
} while (0)
#define FENCE() __builtin_amdgcn_sched_barrier(0)

__global__ __launch_bounds__(256, 4) void hoaf_lds(
    const float* __restrict__ x,
    const float* __restrict__ w1, const float* __restrict__ b1,
    const float* __restrict__ w2, const float* __restrict__ b2,
    const float* __restrict__ w3, const float* __restrict__ b3,
    float* __restrict__ out)
{
    __shared__ __align__(16) float wt[165][8];

    const int tid   = threadIdx.x;
    const int g     = blockIdx.x;
    const int b     = blockIdx.y;
    const int chunk = blockIdx.z;

    for (int idx = tid; idx < 165 * 8; idx += 256) {
        const int f = idx >> 3, o = idx & 7;
        const int ch = g * CPG + o;
        float v;
        if (f < 8)        v = w1[ch * CPG + f];
        else if (f < 44)  v = w2[ch * N2 + (f - 8)];
        else if (f < 164) v = w3[ch * N3 + (f - 44)];
        else              v = b1[ch] + b2[ch] + b3[ch];
        wt[f][o] = v;
    }
    __syncthreads();

    const int q = tid + chunk * 256;
    if (q >= HU) return;

    const vfloat4 b_lo = *reinterpret_cast<const vfloat4*>(&wt[164][0]);
    const vfloat4 b_hi = *reinterpret_cast<const vfloat4*>(&wt[164][4]);

    const size_t base = ((size_t)(b * NGRP + g) * CPG) * HW;
    const vfloat4* x4 = (const vfloat4*)(x + base);
    vfloat4*       o4 = (vfloat4*)(out + base);

    vfloat4 xv[CPG];
#pragma unroll
    for (int c = 0; c < CPG; ++c) xv[c] = x4[(size_t)c * HU + q];

    vfloat4 acc[CPG];
    acc[0] = splat4(b_lo.x); acc[1] = splat4(b_lo.y);
    acc[2] = splat4(b_lo.z); acc[3] = splat4(b_lo.w);
    acc[4] = splat4(b_hi.x); acc[5] = splat4(b_hi.y);
    acc[6] = splat4(b_hi.z); acc[7] = splat4(b_hi.w);

#pragma unroll
    for (int k = 0; k < CPG; k += 2) {
        ACCUM(k, xv[k]);
        ACCUM(k + 1, xv[k + 1]);
        FENCE();
    }

#pragma unroll
    for (int i = 0; i < CPG; ++i) {
#pragma unroll
        for (int j = i; j < CPG; ++j) {
            const vfloat4 p = xv[i] * xv[j];
            ACCUM(8 + idx2(i, j), p);
#pragma unroll
            for (int a = 0; a <= i; ++a) {
                const vfloat4 t = xv[a] * p;
                ACCUM(44 + idx3(a, i, j), t);
            }
            FENCE();
        }
    }

#pragma unroll
    for (int o = 0; o < CPG; ++o) o4[(size_t)o * HU + q] = acc[o];
}

extern "C" void kernel_launch(void* const* d_in, const int* in_sizes, int n_in,
                              void* d_out, int out_size, void* d_ws, size_t ws_size,
                              hipStream_t stream) {
    const float* x  = (const float*)d_in[0];
    const float* w1 = (const float*)d_in[1];
    const float* b1 = (const float*)d_in[2];
    const float* w2 = (const float*)d_in[3];
    const float* b2 = (const float*)d_in[4];
    const float* w3 = (const float*)d_in[5];
    const float* b3 = (const float*)d_in[6];
    float* out = (float*)d_out;
    float* ws  = (float*)d_ws;

    const size_t ws_needed = (size_t)NGRP * WSTRIDE * sizeof(float);  // 169 KB
    if (ws != nullptr && ws_size >= ws_needed) {
        prep_weights<<<dim3(NGRP), dim3(256), 0, stream>>>(w1, b1, w2, b2, w3, b3, ws);
        dim3 grid(NGRP, NB, 8);   // (group, batch, half*4+chunk) — z slowest
        hoaf_sload4<<<grid, dim3(256), 0, stream>>>(x, ws, out);
    } else {
        dim3 grid(NGRP, NB, 4);
        hoaf_lds<<<grid, dim3(256), 0, stream>>>(x, w1, b1, w2, b2, w3, b3, out);
    }
}